// Round 7
// baseline (10272.859 us; speedup 1.0000x reference)
//
#include <hip/hip_runtime.h>
#include <hip/hip_bf16.h>

typedef __attribute__((ext_vector_type(8))) short short8;
typedef __attribute__((ext_vector_type(4))) float f32x4;

// Problem dims
#define NB 64      // batch
#define NS 1024    // seq
#define ND 512     // input dim
#define NH 512     // hidden
#define NG 2048    // 4*NH gate columns
#define M1 65536   // NB*NS rows of the input-projection GEMM

// ws layout (bytes)
#define OFF_A    0L                      // A bf16 [65536][512]           64 MB
#define OFF_XG   67108864L               // xg bf16 [1024][64][2048]     256 MB
#define OFF_WXT  335544320L              // Wxt bf16 [2048][512]           2 MB
#define OFF_WHT  337641472L              // Wht bf16 [2048][512]           2 MB
#define OFF_BC   339738624L              // bcat f32 [2048]                8 KB
#define OFF_HB   339746816L              // hb u32 [4 grp][2][16][256]   128 KB
#define OFF_BAR  339877888L              // ctrl u32: flags[4][32]        512 B

#define OUT_HF   33554432L               // d_out offset of h_final (floats)
#define OUT_CF   33587200L               // d_out offset of c_final

static __device__ __forceinline__ ushort f2bf(float x) {
  union { float f; unsigned u; } v; v.f = x;
  unsigned r = (v.u + 0x7FFFu + ((v.u >> 16) & 1u)) >> 16;
  return (ushort)r;
}
static __device__ __forceinline__ float bf2f(ushort x) {
  union { unsigned u; float f; } v; v.u = ((unsigned)x) << 16; return v.f;
}
static __device__ __forceinline__ float sigm(float x) {
  return 1.0f / (1.0f + __expf(-x));
}
static __device__ __forceinline__ float tanh_fast(float x) {
  return 2.0f / (1.0f + __expf(-2.0f * x)) - 1.0f;
}

// ---------- phase 0a: fp32 -> bf16 convert of inputs ----------
__global__ __launch_bounds__(256) void cvt_in_k(const float* __restrict__ in,
                                                ushort* __restrict__ out) {
  long i = ((long)blockIdx.x * 256 + threadIdx.x) * 8;
  const float4* p = (const float4*)(in + i);
  float4 a = p[0], b = p[1];
  short8 o;
  o[0] = (short)f2bf(a.x); o[1] = (short)f2bf(a.y);
  o[2] = (short)f2bf(a.z); o[3] = (short)f2bf(a.w);
  o[4] = (short)f2bf(b.x); o[5] = (short)f2bf(b.y);
  o[6] = (short)f2bf(b.z); o[7] = (short)f2bf(b.w);
  *(short8*)(out + i) = o;
}

// ---------- phase 0b: transpose+convert weights, pack biases ----------
__global__ __launch_bounds__(256) void prep_w_k(
    const float* __restrict__ Wxi, const float* __restrict__ Whi, const float* __restrict__ bi,
    const float* __restrict__ Wxf, const float* __restrict__ Whf, const float* __restrict__ bff,
    const float* __restrict__ Wxo, const float* __restrict__ Who, const float* __restrict__ bo,
    const float* __restrict__ Wxc, const float* __restrict__ Whc, const float* __restrict__ bc,
    ushort* __restrict__ Wxt, ushort* __restrict__ Wht, float* __restrict__ bcat) {
  int t = blockIdx.x * 256 + threadIdx.x;   // 0 .. 2048*512-1
  int n = t >> 9, k = t & 511;
  int g = n >> 9, col = n & 511;
  const float* wx = (g == 0) ? Wxi : (g == 1) ? Wxf : (g == 2) ? Wxo : Wxc;
  const float* wh = (g == 0) ? Whi : (g == 1) ? Whf : (g == 2) ? Who : Whc;
  Wxt[t] = f2bf(wx[k * 512 + col]);
  Wht[t] = f2bf(wh[k * 512 + col]);
  if (t < 2048) {
    int g2 = t >> 9;
    const float* bp = (g2 == 0) ? bi : (g2 == 1) ? bff : (g2 == 2) ? bo : bc;
    bcat[t] = bp[t & 511];
  }
}

// ---------- phase 1: xg = A @ Wxt^T + b  (bf16 MFMA, 128x128 tiles, BK=32) ----------
__global__ __launch_bounds__(256) void gemm_x_k(const ushort* __restrict__ A,
                                                const ushort* __restrict__ Bt,
                                                const float* __restrict__ bcat,
                                                ushort* __restrict__ xg) {
  __shared__ ushort As[128 * 40];
  __shared__ ushort Bs[128 * 40];
  const int mbase = blockIdx.x * 128;
  const int nbase = blockIdx.y * 128;
  const int tid = threadIdx.x;
  const int lane = tid & 63, wave = tid >> 6;
  const int l15 = lane & 15, q = lane >> 4;
  const int wm = (wave & 1) * 64, wn = (wave >> 1) * 64;

  f32x4 acc[4][4];
#pragma unroll
  for (int j = 0; j < 4; ++j) {
    float bv = bcat[nbase + wn + j * 16 + l15];
#pragma unroll
    for (int i = 0; i < 4; ++i) acc[i][j] = (f32x4){bv, bv, bv, bv};
  }

  const int sr = tid >> 2;
  const int skk = (tid & 3) * 8;

  for (int kt = 0; kt < 16; ++kt) {
    const int kb = kt * 32;
#pragma unroll
    for (int pass = 0; pass < 2; ++pass) {
      int rr = sr + pass * 64;
      *(short8*)&As[rr * 40 + skk] = *(const short8*)&A[(long)(mbase + rr) * 512 + kb + skk];
      *(short8*)&Bs[rr * 40 + skk] = *(const short8*)&Bt[(long)(nbase + rr) * 512 + kb + skk];
    }
    __syncthreads();
    short8 af[4], bfr[4];
#pragma unroll
    for (int i = 0; i < 4; ++i)
      af[i] = *(const short8*)&As[(wm + i * 16 + l15) * 40 + q * 8];
#pragma unroll
    for (int j = 0; j < 4; ++j)
      bfr[j] = *(const short8*)&Bs[(wn + j * 16 + l15) * 40 + q * 8];
#pragma unroll
    for (int i = 0; i < 4; ++i)
#pragma unroll
      for (int j = 0; j < 4; ++j)
        acc[i][j] = __builtin_amdgcn_mfma_f32_16x16x32_bf16(af[i], bfr[j], acc[i][j], 0, 0, 0);
    __syncthreads();
  }

#pragma unroll
  for (int i = 0; i < 4; ++i) {
#pragma unroll
    for (int r = 0; r < 4; ++r) {
      int m = mbase + wm + i * 16 + q * 4 + r;
      int b = m >> 10, s = m & 1023;
      long rowoff = ((long)(s * 64 + b)) * 2048;
#pragma unroll
      for (int j = 0; j < 4; ++j) {
        int n = nbase + wn + j * 16 + l15;
        xg[rowoff + n] = f2bf(acc[i][j][r]);
      }
    }
  }
}

// ---------- phase 2: persistent recurrence, 4 groups x 8 WGs, M=16 all-real ----------
// 32 WGs of 512 threads = 4 groups x 8 roles. Group g owns batches [16g,16g+16)
// (M=16 MFMA tile, ALL rows real - no padding waste); role r = wg>>2 owns h-cols
// [64r,64r+64); wave w (8/WG) owns 8 h-cols. Protocol is the PROVEN R3 one,
// verbatim: AGENT-scope relaxed atomics (MALL), h stores -> __syncthreads (vmcnt
// drain) -> flag publish -> out stores (off critical path) -> xg prefetch ->
// spin(8 group flags) -> __syncthreads. vs R3: sync fan-in 16->8 WGs per group,
// total WGs 128->32 (4x less chip-wide poll traffic), zero padded MFMA rows.
__global__ __launch_bounds__(512, 1) void lstm_rec_k(const ushort* __restrict__ xg,
                                                     const ushort* __restrict__ Wht,
                                                     float* __restrict__ out,
                                                     unsigned* hb, unsigned* ctrl) {
  const int wg = blockIdx.x;          // 0..31
  const int g = wg & 3, r = wg >> 2;  // group, role (0..7)
  const int tid = threadIdx.x;
  const int wave = tid >> 6, lane = tid & 63;   // wave 0..7
  const int l15 = lane & 15, q = lane >> 4;

  unsigned* fl  = ctrl + g * 32;      // 128B per group: private flag line (8 used)
  unsigned* hbg = hb + g * 8192;      // 32KB per group: [2 parity][16 rows][256 u32]
  const ushort* xgg = xg + (long)g * 16 * 2048;  // group's batch-0 column

  // --- B fragments: this wave's 32 gate-cols (8 h-cols x 4 gates, packed pairwise) ---
  // B[k][n]: n(loc) = lane&15, k = kt*32 + q*8 + 0..7
  short8 bfrag[2][16];
  int gcol[2];
#pragma unroll
  for (int p = 0; p < 2; ++p) {
    int nloc = p * 16 + l15;
    gcol[p] = (nloc >> 3) * 512 + r * 64 + wave * 8 + (nloc & 7);
#pragma unroll
    for (int kt = 0; kt < 16; ++kt)
      bfrag[p][kt] = *(const short8*)&Wht[(long)gcol[p] * 512 + kt * 32 + q * 8];
  }
#pragma unroll
  for (int p = 0; p < 2; ++p)
#pragma unroll
    for (int kt = 0; kt < 16; ++kt)
      asm volatile("" : "+v"(bfrag[p][kt]));

  // zero h_0 (parity 0): role r zeroes its 32 u32-cols x 16 rows = 512 slots
  {
    int row = tid >> 5, c = tid & 31;
    __hip_atomic_store(&hbg[row * 256 + r * 32 + c], 0u, __ATOMIC_RELAXED,
                       __HIP_MEMORY_SCOPE_AGENT);
  }
  __syncthreads();                    // drains vmcnt: zeros ack'd at MALL
  if (tid == 0)
    __hip_atomic_store(&fl[r], 1u, __ATOMIC_RELAXED, __HIP_MEMORY_SCOPE_AGENT);

  // prefetch xg[t=0] under the spin (all 16 rows: row = q*4+rr)
  float xpre[2][4];
#pragma unroll
  for (int p = 0; p < 2; ++p)
#pragma unroll
    for (int rr = 0; rr < 4; ++rr)
      xpre[p][rr] = bf2f(xgg[(long)(q * 4 + rr) * 2048 + gcol[p]]);
  if (wave == 0 && lane < 8) {
    while (__hip_atomic_load(&fl[lane], __ATOMIC_RELAXED,
                             __HIP_MEMORY_SCOPE_AGENT) < 1u) {}
  }
  __syncthreads();

  const bool wr = (lane & 8) == 0;          // gate-dedup writer lanes
  const bool wrp = wr && ((lane & 1) == 0); // pair writer lanes (u32 / float2)
  float c4[4] = {0.f, 0.f, 0.f, 0.f};
  float hsave[4] = {0.f, 0.f, 0.f, 0.f};
  float hpsave[4] = {0.f, 0.f, 0.f, 0.f};

  for (int t = 0; t < 1024; ++t) {
    const unsigned* hrow = hbg + (t & 1) * 4096;

    // A fragments: A[m][k], m = lane&15 (batch row, ALL real), k = kt*32+q*8+j
    union { unsigned long long u[2]; short8 s8; } afu[16];
    {
      const unsigned* base = hrow + l15 * 256 + q * 4;
#pragma unroll
      for (int kt = 0; kt < 16; ++kt) {
        const unsigned long long* p = (const unsigned long long*)(base + kt * 16);
        afu[kt].u[0] = __hip_atomic_load(p, __ATOMIC_RELAXED, __HIP_MEMORY_SCOPE_AGENT);
        afu[kt].u[1] = __hip_atomic_load(p + 1, __ATOMIC_RELAXED, __HIP_MEMORY_SCOPE_AGENT);
      }
    }

    f32x4 acc[2];
#pragma unroll
    for (int p = 0; p < 2; ++p)
#pragma unroll
      for (int rr = 0; rr < 4; ++rr)
        acc[p][rr] = xpre[p][rr];

#pragma unroll
    for (int kt = 0; kt < 16; ++kt) {
      acc[0] = __builtin_amdgcn_mfma_f32_16x16x32_bf16(afu[kt].s8, bfrag[0][kt], acc[0], 0, 0, 0);
      acc[1] = __builtin_amdgcn_mfma_f32_16x16x32_bf16(afu[kt].s8, bfrag[1][kt], acc[1], 0, 0, 0);
    }

    // elementwise: lane (bit3=0) has i (acc0), o (acc1); partner lane^8 has f, g.
    unsigned* hdst = hbg + ((t + 1) & 1) * 4096;
#pragma unroll
    for (int rr = 0; rr < 4; ++rr) {
      float a0 = acc[0][rr], a1 = acc[1][rr];
      float o0 = __shfl_xor(a0, 8);
      float o1 = __shfl_xor(a1, 8);
      float pi = wr ? a0 : o0;
      float pf = wr ? o0 : a0;
      float po = wr ? a1 : o1;
      float pg = wr ? o1 : a1;
      float ig = sigm(pi), fg = sigm(pf), og = sigm(po), gg = tanh_fast(pg);
      float cc = fg * c4[rr] + ig * gg;
      c4[rr] = cc;
      float hn = og * tanh_fast(cc);
      float hnp = __shfl_xor(hn, 1);        // partner col's h
      hsave[rr] = hn;
      hpsave[rr] = hnp;
      if (wrp) {
        unsigned pack = (unsigned)f2bf(hn) | ((unsigned)f2bf(hnp) << 16);
        __hip_atomic_store(&hdst[(q * 4 + rr) * 256 + r * 32 + wave * 4 + ((lane & 6) >> 1)],
                           pack, __ATOMIC_RELAXED, __HIP_MEMORY_SCOPE_AGENT);
      }
    }

    if (t < 1023) {
      __syncthreads();                      // drains vmcnt(0): h stores ack'd at MALL
      if (tid == 0)
        __hip_atomic_store(&fl[r], (unsigned)(t + 2), __ATOMIC_RELAXED,
                           __HIP_MEMORY_SCOPE_AGENT);
    }

    // out stores after flag publish: retire during next step, off critical path
    if (wrp) {
#pragma unroll
      for (int rr = 0; rr < 4; ++rr)
        *(float2*)&out[(long)(g * 16 + q * 4 + rr) * (NS * NH) + (long)t * NH +
                       r * 64 + wave * 8 + (lane & 6)] =
            make_float2(hsave[rr], hpsave[rr]);
    }

    if (t < 1023) {
      // prefetch next step's xg under the spin (read-only, cached)
      long xb2 = ((long)(t + 1) * 64) * 2048;
#pragma unroll
      for (int p = 0; p < 2; ++p)
#pragma unroll
        for (int rr = 0; rr < 4; ++rr)
          xpre[p][rr] = bf2f(xgg[xb2 + (long)(q * 4 + rr) * 2048 + gcol[p]]);
      if (wave == 0 && lane < 8) {
        unsigned tgt = (unsigned)(t + 2);
        while (__hip_atomic_load(&fl[lane], __ATOMIC_RELAXED,
                                 __HIP_MEMORY_SCOPE_AGENT) < tgt) {}
      }
      __syncthreads();
    }
  }

  // final h / c state (t = 1023 values still in registers)
  if (wr) {
    int hcol = r * 64 + wave * 8 + (lane & 7);
#pragma unroll
    for (int rr = 0; rr < 4; ++rr) {
      int b = g * 16 + q * 4 + rr;
      out[OUT_HF + (long)b * 512 + hcol] = hsave[rr];
      out[OUT_CF + (long)b * 512 + hcol] = c4[rr];
    }
  }
}

extern "C" void kernel_launch(void* const* d_in, const int* in_sizes, int n_in,
                              void* d_out, int out_size, void* d_ws, size_t ws_size,
                              hipStream_t stream) {
  const float* inputs = (const float*)d_in[0];
  const float* Wxi = (const float*)d_in[1];
  const float* Whi = (const float*)d_in[2];
  const float* bi  = (const float*)d_in[3];
  const float* Wxf = (const float*)d_in[4];
  const float* Whf = (const float*)d_in[5];
  const float* bff = (const float*)d_in[6];
  const float* Wxo = (const float*)d_in[7];
  const float* Who = (const float*)d_in[8];
  const float* bo  = (const float*)d_in[9];
  const float* Wxc = (const float*)d_in[10];
  const float* Whc = (const float*)d_in[11];
  const float* bc  = (const float*)d_in[12];

  char* ws = (char*)d_ws;
  ushort*  Abf  = (ushort*)(ws + OFF_A);
  ushort*  xgp  = (ushort*)(ws + OFF_XG);
  ushort*  Wxt  = (ushort*)(ws + OFF_WXT);
  ushort*  Whtp = (ushort*)(ws + OFF_WHT);
  float*   bcat = (float*)(ws + OFF_BC);
  unsigned* hb  = (unsigned*)(ws + OFF_HB);
  unsigned* ctrl = (unsigned*)(ws + OFF_BAR);

  hipMemsetAsync(ctrl, 0, 512, stream);    // flags[4][32]

  cvt_in_k<<<16384, 256, 0, stream>>>(inputs, Abf);
  prep_w_k<<<4096, 256, 0, stream>>>(Wxi, Whi, bi, Wxf, Whf, bff,
                                     Wxo, Who, bo, Wxc, Whc, bc,
                                     Wxt, Whtp, bcat);
  dim3 g1(M1 / 128, NG / 128);                                      // 512 x 16
  gemm_x_k<<<g1, 256, 0, stream>>>(Abf, Wxt, bcat, xgp);
  lstm_rec_k<<<32, 512, 0, stream>>>(xgp, Whtp, (float*)d_out, hb, ctrl);
}

// Round 8
// 5287.374 us; speedup vs baseline: 1.9429x; 1.9429x over previous
//
#include <hip/hip_runtime.h>
#include <hip/hip_bf16.h>

typedef __attribute__((ext_vector_type(8))) short short8;
typedef __attribute__((ext_vector_type(4))) float f32x4;

// Problem dims
#define NB 64      // batch
#define NS 1024    // seq
#define ND 512     // input dim
#define NH 512     // hidden
#define NG 2048    // 4*NH gate columns
#define M1 65536   // NB*NS rows of the input-projection GEMM

// ws layout (bytes)
#define OFF_A    0L                      // A bf16 [65536][512]           64 MB
#define OFF_XG   67108864L               // xg bf16 [1024][64][2048]     256 MB
#define OFF_WXT  335544320L              // Wxt bf16 [2048][512]           2 MB
#define OFF_WHT  337641472L              // Wht bf16 [2048][512]           2 MB
#define OFF_BC   339738624L              // bcat f32 [2048]                8 KB
#define OFF_HB   339746816L              // hb u32 [8 grp][2][8][256]    128 KB
#define OFF_BAR  339877888L              // ctrl u32: flags[8][64]         2 KB

#define OUT_HF   33554432L               // d_out offset of h_final (floats)
#define OUT_CF   33587200L               // d_out offset of c_final

static __device__ __forceinline__ ushort f2bf(float x) {
  union { float f; unsigned u; } v; v.f = x;
  unsigned r = (v.u + 0x7FFFu + ((v.u >> 16) & 1u)) >> 16;
  return (ushort)r;
}
static __device__ __forceinline__ float bf2f(ushort x) {
  union { unsigned u; float f; } v; v.u = ((unsigned)x) << 16; return v.f;
}
static __device__ __forceinline__ float sigm(float x) {
  return 1.0f / (1.0f + __expf(-x));
}
static __device__ __forceinline__ float tanh_fast(float x) {
  return 2.0f / (1.0f + __expf(-2.0f * x)) - 1.0f;
}

// ---------- phase 0a: fp32 -> bf16 convert of inputs ----------
__global__ __launch_bounds__(256) void cvt_in_k(const float* __restrict__ in,
                                                ushort* __restrict__ out) {
  long i = ((long)blockIdx.x * 256 + threadIdx.x) * 8;
  const float4* p = (const float4*)(in + i);
  float4 a = p[0], b = p[1];
  short8 o;
  o[0] = (short)f2bf(a.x); o[1] = (short)f2bf(a.y);
  o[2] = (short)f2bf(a.z); o[3] = (short)f2bf(a.w);
  o[4] = (short)f2bf(b.x); o[5] = (short)f2bf(b.y);
  o[6] = (short)f2bf(b.z); o[7] = (short)f2bf(b.w);
  *(short8*)(out + i) = o;
}

// ---------- phase 0b: transpose+convert weights, pack biases ----------
__global__ __launch_bounds__(256) void prep_w_k(
    const float* __restrict__ Wxi, const float* __restrict__ Whi, const float* __restrict__ bi,
    const float* __restrict__ Wxf, const float* __restrict__ Whf, const float* __restrict__ bff,
    const float* __restrict__ Wxo, const float* __restrict__ Who, const float* __restrict__ bo,
    const float* __restrict__ Wxc, const float* __restrict__ Whc, const float* __restrict__ bc,
    ushort* __restrict__ Wxt, ushort* __restrict__ Wht, float* __restrict__ bcat) {
  int t = blockIdx.x * 256 + threadIdx.x;   // 0 .. 2048*512-1
  int n = t >> 9, k = t & 511;
  int g = n >> 9, col = n & 511;
  const float* wx = (g == 0) ? Wxi : (g == 1) ? Wxf : (g == 2) ? Wxo : Wxc;
  const float* wh = (g == 0) ? Whi : (g == 1) ? Whf : (g == 2) ? Who : Whc;
  Wxt[t] = f2bf(wx[k * 512 + col]);
  Wht[t] = f2bf(wh[k * 512 + col]);
  if (t < 2048) {
    int g2 = t >> 9;
    const float* bp = (g2 == 0) ? bi : (g2 == 1) ? bff : (g2 == 2) ? bo : bc;
    bcat[t] = bp[t & 511];
  }
}

// ---------- phase 1: xg = A @ Wxt^T + b  (bf16 MFMA, 128x128 tiles, BK=32) ----------
__global__ __launch_bounds__(256) void gemm_x_k(const ushort* __restrict__ A,
                                                const ushort* __restrict__ Bt,
                                                const float* __restrict__ bcat,
                                                ushort* __restrict__ xg) {
  __shared__ ushort As[128 * 40];
  __shared__ ushort Bs[128 * 40];
  const int mbase = blockIdx.x * 128;
  const int nbase = blockIdx.y * 128;
  const int tid = threadIdx.x;
  const int lane = tid & 63, wave = tid >> 6;
  const int l15 = lane & 15, q = lane >> 4;
  const int wm = (wave & 1) * 64, wn = (wave >> 1) * 64;

  f32x4 acc[4][4];
#pragma unroll
  for (int j = 0; j < 4; ++j) {
    float bv = bcat[nbase + wn + j * 16 + l15];
#pragma unroll
    for (int i = 0; i < 4; ++i) acc[i][j] = (f32x4){bv, bv, bv, bv};
  }

  const int sr = tid >> 2;
  const int skk = (tid & 3) * 8;

  for (int kt = 0; kt < 16; ++kt) {
    const int kb = kt * 32;
#pragma unroll
    for (int pass = 0; pass < 2; ++pass) {
      int rr = sr + pass * 64;
      *(short8*)&As[rr * 40 + skk] = *(const short8*)&A[(long)(mbase + rr) * 512 + kb + skk];
      *(short8*)&Bs[rr * 40 + skk] = *(const short8*)&Bt[(long)(nbase + rr) * 512 + kb + skk];
    }
    __syncthreads();
    short8 af[4], bfr[4];
#pragma unroll
    for (int i = 0; i < 4; ++i)
      af[i] = *(const short8*)&As[(wm + i * 16 + l15) * 40 + q * 8];
#pragma unroll
    for (int j = 0; j < 4; ++j)
      bfr[j] = *(const short8*)&Bs[(wn + j * 16 + l15) * 40 + q * 8];
#pragma unroll
    for (int i = 0; i < 4; ++i)
#pragma unroll
      for (int j = 0; j < 4; ++j)
        acc[i][j] = __builtin_amdgcn_mfma_f32_16x16x32_bf16(af[i], bfr[j], acc[i][j], 0, 0, 0);
    __syncthreads();
  }

#pragma unroll
  for (int i = 0; i < 4; ++i) {
#pragma unroll
    for (int r = 0; r < 4; ++r) {
      int m = mbase + wm + i * 16 + q * 4 + r;
      int b = m >> 10, s = m & 1023;
      long rowoff = ((long)(s * 64 + b)) * 2048;
#pragma unroll
      for (int j = 0; j < 4; ++j) {
        int n = nbase + wn + j * 16 + l15;
        xg[rowoff + n] = f2bf(acc[i][j][r]);
      }
    }
  }
}

// ---------- phase 2: persistent recurrence, BARRIER-FREE per-wave flags ----------
// R3 geometry verbatim: 128 WGs = 8 groups x 16 roles; group g = wg&7 owns
// batches [8g,8g+8) (M=16 tile, rows 8..15 zero-padded); role r = wg>>3 owns
// h-cols [32r,32r+32); wave w owns 8. DIFFERENCE vs R3 (4638us): zero
// __syncthreads in the loop. R3's two barriers each forced a vmcnt(0) drain,
// putting HBM out-stores + xg prefetch (~900cy each) AND 4-wave coupling on
// the critical path. Here every wave free-runs:
//   poll 64 per-wave flags (lane l polls flag l, __all ballot) ->
//   32 h-loads -> MFMA -> elementwise ->
//   tail asm: 4 h-stores, vmcnt(0) [h only: out/prefetch issued after], flag ->
//   out-stores + xg prefetch (retire under next spin, never drained on-chain).
// Safety: flags monotone, publish unconditional -> no deadlock. Parity-2 safe:
// wave flag = t+1 implies its h_t loads retired (vmcnt(0) before MFMA), so no
// producer can overwrite parity t&1 while any reader still needs it.
// t=0 uses implicit h_0 = 0 (no loads, no init, no start handshake).
__global__ __launch_bounds__(256, 1) void lstm_rec_k(const ushort* __restrict__ xg,
                                                     const ushort* __restrict__ Wht,
                                                     float* __restrict__ out,
                                                     unsigned* hb, unsigned* ctrl) {
  const int wg = blockIdx.x;          // 0..127
  const int g = wg & 7, r = wg >> 3;  // group, role
  const int tid = threadIdx.x;
  const int wave = tid >> 6, lane = tid & 63;
  const int l15 = lane & 15, q = lane >> 4;

  unsigned* fl  = ctrl + g * 64;      // 64 per-wave flags: idx = role*4 + wave
  unsigned* hbg = hb + g * 4096;      // [2 parity][8 rows][256 u32]
  const ushort* xgg = xg + (long)g * 8 * 2048;  // group's batch-0 column

  // --- B fragments: this wave's 32 gate-cols (gates packed pairwise), pinned ---
  // B[k][n]: n(loc) = lane&15, k = kt*32 + q*8 + 0..7
  short8 bfrag[2][16];
  int gcol[2];
#pragma unroll
  for (int p = 0; p < 2; ++p) {
    int nloc = p * 16 + l15;
    gcol[p] = (nloc >> 3) * 512 + r * 32 + wave * 8 + (nloc & 7);
#pragma unroll
    for (int kt = 0; kt < 16; ++kt)
      bfrag[p][kt] = *(const short8*)&Wht[(long)gcol[p] * 512 + kt * 32 + q * 8];
  }
#pragma unroll
  for (int p = 0; p < 2; ++p)
#pragma unroll
    for (int kt = 0; kt < 16; ++kt)
      asm volatile("" : "+v"(bfrag[p][kt]));

  // prefetch xg[t=0] (h_0 == 0 implicit: no loads, no handshake)
  float xpre[2][4] = {{0.f, 0.f, 0.f, 0.f}, {0.f, 0.f, 0.f, 0.f}};
  if (q < 2) {
#pragma unroll
    for (int p = 0; p < 2; ++p)
#pragma unroll
      for (int rr = 0; rr < 4; ++rr)
        xpre[p][rr] = bf2f(xgg[(long)(q * 4 + rr) * 2048 + gcol[p]]);
  }

  const bool wr = (lane & 8) == 0;          // gate-dedup writer lanes
  const bool wrp = wr && ((lane & 1) == 0); // pair writer lanes
  unsigned* flp = fl + r * 4 + wave;        // this wave's own flag
  float c4[4] = {0.f, 0.f, 0.f, 0.f};
  float hsave[4] = {0.f, 0.f, 0.f, 0.f};
  float hpsave[4] = {0.f, 0.f, 0.f, 0.f};

  for (int t = 0; t < 1024; ++t) {
    union { unsigned long long u[2]; short8 s8; } afu[16];
#pragma unroll
    for (int kt = 0; kt < 16; ++kt) { afu[kt].u[0] = 0ull; afu[kt].u[1] = 0ull; }

    if (t > 0) {
      // barrier-free group wait: lane l polls producer-wave flag l
      const unsigned tgt = (unsigned)t;
      for (;;) {
        unsigned f = __hip_atomic_load(&fl[lane], __ATOMIC_RELAXED,
                                       __HIP_MEMORY_SCOPE_AGENT);
        if (__all((int)(f >= tgt))) break;
      }
      asm volatile("" ::: "memory");        // no load hoisting above the wait

      if (l15 < 8) {
        const unsigned* base = hbg + (t & 1) * 2048 + l15 * 256 + q * 4;
#pragma unroll
        for (int kt = 0; kt < 16; ++kt) {
          const unsigned long long* p = (const unsigned long long*)(base + kt * 16);
          afu[kt].u[0] = __hip_atomic_load(p, __ATOMIC_RELAXED, __HIP_MEMORY_SCOPE_AGENT);
          afu[kt].u[1] = __hip_atomic_load(p + 1, __ATOMIC_RELAXED, __HIP_MEMORY_SCOPE_AGENT);
        }
      }
    }

    f32x4 acc[2];
#pragma unroll
    for (int p = 0; p < 2; ++p)
#pragma unroll
      for (int rr = 0; rr < 4; ++rr)
        acc[p][rr] = xpre[p][rr];

#pragma unroll
    for (int kt = 0; kt < 16; ++kt) {
      acc[0] = __builtin_amdgcn_mfma_f32_16x16x32_bf16(afu[kt].s8, bfrag[0][kt], acc[0], 0, 0, 0);
      acc[1] = __builtin_amdgcn_mfma_f32_16x16x32_bf16(afu[kt].s8, bfrag[1][kt], acc[1], 0, 0, 0);
    }

    // elementwise: lane (bit3=0) has i (acc0), o (acc1); partner lane^8 has f, g.
    unsigned packs[4];
#pragma unroll
    for (int rr = 0; rr < 4; ++rr) {
      float a0 = acc[0][rr], a1 = acc[1][rr];
      float o0 = __shfl_xor(a0, 8);
      float o1 = __shfl_xor(a1, 8);
      float pi = wr ? a0 : o0;
      float pf = wr ? o0 : a0;
      float po = wr ? a1 : o1;
      float pg = wr ? o1 : a1;
      float ig = sigm(pi), fg = sigm(pf), og = sigm(po), gg = tanh_fast(pg);
      float cc = fg * c4[rr] + ig * gg;
      c4[rr] = cc;
      float hn = og * tanh_fast(cc);
      float hnp = __shfl_xor(hn, 1);        // partner col's h
      hsave[rr] = hn;
      hpsave[rr] = hnp;
      packs[rr] = (unsigned)f2bf(hn) | ((unsigned)f2bf(hnp) << 16);
    }

    // ---- producer tail: h stores -> vmcnt(0) (h only) -> per-wave flag ----
    if (t < 1023 && wrp && q < 2) {
      unsigned* hd = hbg + ((t + 1) & 1) * 2048 + q * 1024 + r * 16 + wave * 4 +
                     ((lane & 6) >> 1);     // row stride 256 u32 = 1024 B
      asm volatile(
          "global_store_dword %[a], %[d0], off sc0 sc1\n\t"
          "global_store_dword %[a], %[d1], off offset:1024 sc0 sc1\n\t"
          "global_store_dword %[a], %[d2], off offset:2048 sc0 sc1\n\t"
          "global_store_dword %[a], %[d3], off offset:3072 sc0 sc1\n\t"
          "s_waitcnt vmcnt(0)\n\t"
          "global_store_dword %[f], %[tv], off sc0 sc1"
          :: [a]"v"(hd), [d0]"v"(packs[0]), [d1]"v"(packs[1]),
             [d2]"v"(packs[2]), [d3]"v"(packs[3]),
             [f]"v"(flp), [tv]"v"((unsigned)(t + 1))
          : "memory");
    }

    // out stores + xg prefetch AFTER the flag: retire under the next spin,
    // never drained on the critical path (no barriers exist to drain them).
    if (wrp && q < 2) {
#pragma unroll
      for (int rr = 0; rr < 4; ++rr)
        *(float2*)&out[(long)(g * 8 + q * 4 + rr) * (NS * NH) + (long)t * NH +
                       r * 32 + wave * 8 + (lane & 6)] =
            make_float2(hsave[rr], hpsave[rr]);
    }

    if (t < 1023) {
      long xb2 = ((long)(t + 1) * 64) * 2048;
      if (q < 2) {
#pragma unroll
        for (int p = 0; p < 2; ++p)
#pragma unroll
          for (int rr = 0; rr < 4; ++rr)
            xpre[p][rr] = bf2f(xgg[xb2 + (long)(q * 4 + rr) * 2048 + gcol[p]]);
      }
    }
  }

  // final h / c state (t = 1023 values still in registers)
  if (wr && q < 2) {
    int hcol = r * 32 + wave * 8 + (lane & 7);
#pragma unroll
    for (int rr = 0; rr < 4; ++rr) {
      int b = g * 8 + q * 4 + rr;
      out[OUT_HF + (long)b * 512 + hcol] = hsave[rr];
      out[OUT_CF + (long)b * 512 + hcol] = c4[rr];
    }
  }
}

extern "C" void kernel_launch(void* const* d_in, const int* in_sizes, int n_in,
                              void* d_out, int out_size, void* d_ws, size_t ws_size,
                              hipStream_t stream) {
  const float* inputs = (const float*)d_in[0];
  const float* Wxi = (const float*)d_in[1];
  const float* Whi = (const float*)d_in[2];
  const float* bi  = (const float*)d_in[3];
  const float* Wxf = (const float*)d_in[4];
  const float* Whf = (const float*)d_in[5];
  const float* bff = (const float*)d_in[6];
  const float* Wxo = (const float*)d_in[7];
  const float* Who = (const float*)d_in[8];
  const float* bo  = (const float*)d_in[9];
  const float* Wxc = (const float*)d_in[10];
  const float* Whc = (const float*)d_in[11];
  const float* bc  = (const float*)d_in[12];

  char* ws = (char*)d_ws;
  ushort*  Abf  = (ushort*)(ws + OFF_A);
  ushort*  xgp  = (ushort*)(ws + OFF_XG);
  ushort*  Wxt  = (ushort*)(ws + OFF_WXT);
  ushort*  Whtp = (ushort*)(ws + OFF_WHT);
  float*   bcat = (float*)(ws + OFF_BC);
  unsigned* hb  = (unsigned*)(ws + OFF_HB);
  unsigned* ctrl = (unsigned*)(ws + OFF_BAR);

  hipMemsetAsync(ctrl, 0, 2048, stream);   // flags[8][64]

  cvt_in_k<<<16384, 256, 0, stream>>>(inputs, Abf);
  prep_w_k<<<4096, 256, 0, stream>>>(Wxi, Whi, bi, Wxf, Whf, bff,
                                     Wxo, Who, bo, Wxc, Whc, bc,
                                     Wxt, Whtp, bcat);
  dim3 g1(M1 / 128, NG / 128);                                      // 512 x 16
  gemm_x_k<<<g1, 256, 0, stream>>>(Abf, Wxt, bcat, xgp);
  lstm_rec_k<<<128, 256, 0, stream>>>(xgp, Whtp, (float*)d_out, hb, ctrl);
}

// Round 9
// 3374.655 us; speedup vs baseline: 3.0441x; 1.5668x over previous
//
#include <hip/hip_runtime.h>
#include <hip/hip_bf16.h>

typedef __attribute__((ext_vector_type(8))) short short8;
typedef __attribute__((ext_vector_type(4))) float f32x4;
typedef __attribute__((ext_vector_type(4))) unsigned int u32x4;

// Problem dims
#define NB 64      // batch
#define NS 1024    // seq
#define ND 512     // input dim
#define NH 512     // hidden
#define NG 2048    // 4*NH gate columns
#define M1 65536   // NB*NS rows of the input-projection GEMM

// ws layout (bytes)
#define OFF_A    0L                      // A bf16 [65536][512]           64 MB
#define OFF_XG   67108864L               // xg bf16 [1024][64][2048]     256 MB
#define OFF_WXT  335544320L              // Wxt bf16 [2048][512]           2 MB
#define OFF_WHT  337641472L              // Wht bf16 [2048][512]           2 MB
#define OFF_BC   339738624L              // bcat f32 [2048]                8 KB
#define OFF_HB   339746816L              // hb u32 [8 grp][2][8][256]    128 KB
#define OFF_BAR  339877888L              // ctrl u32: flags[8][32]         1 KB

#define OUT_HF   33554432L               // d_out offset of h_final (floats)
#define OUT_CF   33587200L               // d_out offset of c_final

#define LDS_STRIDE 264                   // u32 row stride (1056B): read pattern max 2-way

static __device__ __forceinline__ ushort f2bf(float x) {
  union { float f; unsigned u; } v; v.f = x;
  unsigned r = (v.u + 0x7FFFu + ((v.u >> 16) & 1u)) >> 16;
  return (ushort)r;
}
static __device__ __forceinline__ float bf2f(ushort x) {
  union { unsigned u; float f; } v; v.u = ((unsigned)x) << 16; return v.f;
}
static __device__ __forceinline__ float sigm(float x) {
  return 1.0f / (1.0f + __expf(-x));
}
static __device__ __forceinline__ float tanh_fast(float x) {
  return 2.0f / (1.0f + __expf(-2.0f * x)) - 1.0f;
}

// ---------- phase 0a: fp32 -> bf16 convert of inputs ----------
__global__ __launch_bounds__(256) void cvt_in_k(const float* __restrict__ in,
                                                ushort* __restrict__ out) {
  long i = ((long)blockIdx.x * 256 + threadIdx.x) * 8;
  const float4* p = (const float4*)(in + i);
  float4 a = p[0], b = p[1];
  short8 o;
  o[0] = (short)f2bf(a.x); o[1] = (short)f2bf(a.y);
  o[2] = (short)f2bf(a.z); o[3] = (short)f2bf(a.w);
  o[4] = (short)f2bf(b.x); o[5] = (short)f2bf(b.y);
  o[6] = (short)f2bf(b.z); o[7] = (short)f2bf(b.w);
  *(short8*)(out + i) = o;
}

// ---------- phase 0b: transpose+convert weights, pack biases ----------
__global__ __launch_bounds__(256) void prep_w_k(
    const float* __restrict__ Wxi, const float* __restrict__ Whi, const float* __restrict__ bi,
    const float* __restrict__ Wxf, const float* __restrict__ Whf, const float* __restrict__ bff,
    const float* __restrict__ Wxo, const float* __restrict__ Who, const float* __restrict__ bo,
    const float* __restrict__ Wxc, const float* __restrict__ Whc, const float* __restrict__ bc,
    ushort* __restrict__ Wxt, ushort* __restrict__ Wht, float* __restrict__ bcat) {
  int t = blockIdx.x * 256 + threadIdx.x;   // 0 .. 2048*512-1
  int n = t >> 9, k = t & 511;
  int g = n >> 9, col = n & 511;
  const float* wx = (g == 0) ? Wxi : (g == 1) ? Wxf : (g == 2) ? Wxo : Wxc;
  const float* wh = (g == 0) ? Whi : (g == 1) ? Whf : (g == 2) ? Who : Whc;
  Wxt[t] = f2bf(wx[k * 512 + col]);
  Wht[t] = f2bf(wh[k * 512 + col]);
  if (t < 2048) {
    int g2 = t >> 9;
    const float* bp = (g2 == 0) ? bi : (g2 == 1) ? bff : (g2 == 2) ? bo : bc;
    bcat[t] = bp[t & 511];
  }
}

// ---------- phase 1: xg = A @ Wxt^T + b  (bf16 MFMA, 128x128 tiles, BK=32) ----------
__global__ __launch_bounds__(256) void gemm_x_k(const ushort* __restrict__ A,
                                                const ushort* __restrict__ Bt,
                                                const float* __restrict__ bcat,
                                                ushort* __restrict__ xg) {
  __shared__ ushort As[128 * 40];
  __shared__ ushort Bs[128 * 40];
  const int mbase = blockIdx.x * 128;
  const int nbase = blockIdx.y * 128;
  const int tid = threadIdx.x;
  const int lane = tid & 63, wave = tid >> 6;
  const int l15 = lane & 15, q = lane >> 4;
  const int wm = (wave & 1) * 64, wn = (wave >> 1) * 64;

  f32x4 acc[4][4];
#pragma unroll
  for (int j = 0; j < 4; ++j) {
    float bv = bcat[nbase + wn + j * 16 + l15];
#pragma unroll
    for (int i = 0; i < 4; ++i) acc[i][j] = (f32x4){bv, bv, bv, bv};
  }

  const int sr = tid >> 2;
  const int skk = (tid & 3) * 8;

  for (int kt = 0; kt < 16; ++kt) {
    const int kb = kt * 32;
#pragma unroll
    for (int pass = 0; pass < 2; ++pass) {
      int rr = sr + pass * 64;
      *(short8*)&As[rr * 40 + skk] = *(const short8*)&A[(long)(mbase + rr) * 512 + kb + skk];
      *(short8*)&Bs[rr * 40 + skk] = *(const short8*)&Bt[(long)(nbase + rr) * 512 + kb + skk];
    }
    __syncthreads();
    short8 af[4], bfr[4];
#pragma unroll
    for (int i = 0; i < 4; ++i)
      af[i] = *(const short8*)&As[(wm + i * 16 + l15) * 40 + q * 8];
#pragma unroll
    for (int j = 0; j < 4; ++j)
      bfr[j] = *(const short8*)&Bs[(wn + j * 16 + l15) * 40 + q * 8];
#pragma unroll
    for (int i = 0; i < 4; ++i)
#pragma unroll
      for (int j = 0; j < 4; ++j)
        acc[i][j] = __builtin_amdgcn_mfma_f32_16x16x32_bf16(af[i], bfr[j], acc[i][j], 0, 0, 0);
    __syncthreads();
  }

#pragma unroll
  for (int i = 0; i < 4; ++i) {
#pragma unroll
    for (int r = 0; r < 4; ++r) {
      int m = mbase + wm + i * 16 + q * 4 + r;
      int b = m >> 10, s = m & 1023;
      long rowoff = ((long)(s * 64 + b)) * 2048;
#pragma unroll
      for (int j = 0; j < 4; ++j) {
        int n = nbase + wn + j * 16 + l15;
        xg[rowoff + n] = f2bf(acc[i][j][r]);
      }
    }
  }
}

// ---------- phase 2: persistent recurrence, R3 protocol + LDS slab dedup ----------
// 128 WGs = 8 groups x 16 roles (R3 champion geometry, protocol verbatim).
// NEW vs R3: the 8KB h_t slab is loaded from the MALL ONCE per WG (256 threads,
// coalesced dwordx4 sc0 sc1 -> 64 unique line-reads) and staged in LDS; each
// wave then builds MFMA fragments via ds_read_b128. Eliminates the 4x broadcast
// (4 waves x full slab) that dominated MALL service time in R3/R7/R8.
// Safety: identical flag/drain ordering to R3; a WG's flag=t+1 implies its
// staging loads of parity t&1 retired (vmcnt(0) before stage-barrier), so
// parity reuse is race-free. LDS single-buffered: reads of iter t complete
// before iter t+1's staging (separated by drain+spin barriers).
__global__ __launch_bounds__(256, 1) void lstm_rec_k(const ushort* __restrict__ xg,
                                                     const ushort* __restrict__ Wht,
                                                     float* __restrict__ out,
                                                     unsigned* hb, unsigned* ctrl) {
  const int wg = blockIdx.x;          // 0..127
  const int g = wg & 7, r = wg >> 3;  // group, role
  const int tid = threadIdx.x;
  const int wave = tid >> 6, lane = tid & 63;
  const int l15 = lane & 15, q = lane >> 4;

  __shared__ unsigned hs[8 * LDS_STRIDE];   // staged h slab, 8 rows x 256 u32 (+pad)

  unsigned* fl  = ctrl + g * 32;      // 128B per group: private flag line (16 used)
  unsigned* hbg = hb + g * 4096;      // [2 parity][8 rows][256 u32]
  const ushort* xgg = xg + (long)g * 8 * 2048;  // group's batch-0 column

  // --- B fragments: this wave's 32 gate-cols (gates packed pairwise), pinned ---
  short8 bfrag[2][16];
  int gcol[2];
#pragma unroll
  for (int p = 0; p < 2; ++p) {
    int nloc = p * 16 + l15;
    gcol[p] = (nloc >> 3) * 512 + r * 32 + wave * 8 + (nloc & 7);
#pragma unroll
    for (int kt = 0; kt < 16; ++kt)
      bfrag[p][kt] = *(const short8*)&Wht[(long)gcol[p] * 512 + kt * 32 + q * 8];
  }
#pragma unroll
  for (int p = 0; p < 2; ++p)
#pragma unroll
    for (int kt = 0; kt < 16; ++kt)
      asm volatile("" : "+v"(bfrag[p][kt]));

  // prefetch xg[t=0] (h_0 == 0 implicit: no loads, no init handshake)
  float xpre[2][4] = {{0.f, 0.f, 0.f, 0.f}, {0.f, 0.f, 0.f, 0.f}};
  if (q < 2) {
#pragma unroll
    for (int p = 0; p < 2; ++p)
#pragma unroll
      for (int rr = 0; rr < 4; ++rr)
        xpre[p][rr] = bf2f(xgg[(long)(q * 4 + rr) * 2048 + gcol[p]]);
  }

  const bool wr = (lane & 8) == 0;          // gate-dedup writer lanes
  const bool wrp = wr && ((lane & 1) == 0); // pair writer lanes (u32 / float2)
  float c4[4] = {0.f, 0.f, 0.f, 0.f};
  float hsave[4] = {0.f, 0.f, 0.f, 0.f};
  float hpsave[4] = {0.f, 0.f, 0.f, 0.f};

  // staging chunk ids: thread handles 16B chunks tid and tid+256 (512 total)
  const int c0 = tid, c1 = tid + 256;
  const int l0 = (c0 >> 6) * LDS_STRIDE + (c0 & 63) * 4;  // LDS u32 index
  const int l1 = (c1 >> 6) * LDS_STRIDE + (c1 & 63) * 4;

  for (int t = 0; t < 1024; ++t) {
    union { unsigned long long u[2]; short8 s8; } afu[16];

    if (t > 0) {
      // ---- cooperative slab staging: 8KB loaded ONCE per WG ----
      const unsigned* gb = hbg + (t & 1) * 2048;
      u32x4 va, vb;
      asm volatile(
          "global_load_dwordx4 %0, %2, off sc0 sc1\n\t"
          "global_load_dwordx4 %1, %3, off sc0 sc1"
          : "=&v"(va), "=&v"(vb)
          : "v"(gb + c0 * 4), "v"(gb + c1 * 4)
          : "memory");
      asm volatile("s_waitcnt vmcnt(0)" ::: "memory");
      *(u32x4*)&hs[l0] = va;
      *(u32x4*)&hs[l1] = vb;
      __syncthreads();                      // slab staged, LDS visible

      if (l15 < 8) {
        const unsigned* lb = &hs[l15 * LDS_STRIDE + q * 4];
#pragma unroll
        for (int kt = 0; kt < 16; ++kt)
          afu[kt].s8 = *(const short8*)(lb + kt * 16);
      } else {
#pragma unroll
        for (int kt = 0; kt < 16; ++kt) { afu[kt].u[0] = 0ull; afu[kt].u[1] = 0ull; }
      }
    } else {
#pragma unroll
      for (int kt = 0; kt < 16; ++kt) { afu[kt].u[0] = 0ull; afu[kt].u[1] = 0ull; }
    }

    f32x4 acc[2];
#pragma unroll
    for (int p = 0; p < 2; ++p)
#pragma unroll
      for (int rr = 0; rr < 4; ++rr)
        acc[p][rr] = xpre[p][rr];

#pragma unroll
    for (int kt = 0; kt < 16; ++kt) {
      acc[0] = __builtin_amdgcn_mfma_f32_16x16x32_bf16(afu[kt].s8, bfrag[0][kt], acc[0], 0, 0, 0);
      acc[1] = __builtin_amdgcn_mfma_f32_16x16x32_bf16(afu[kt].s8, bfrag[1][kt], acc[1], 0, 0, 0);
    }

    // elementwise: lane (bit3=0) has i (acc0), o (acc1); partner lane^8 has f, g.
    unsigned* hdst = hbg + ((t + 1) & 1) * 2048;
#pragma unroll
    for (int rr = 0; rr < 4; ++rr) {
      float a0 = acc[0][rr], a1 = acc[1][rr];
      float o0 = __shfl_xor(a0, 8);
      float o1 = __shfl_xor(a1, 8);
      float pi = wr ? a0 : o0;
      float pf = wr ? o0 : a0;
      float po = wr ? a1 : o1;
      float pg = wr ? o1 : a1;
      float ig = sigm(pi), fg = sigm(pf), og = sigm(po), gg = tanh_fast(pg);
      float cc = fg * c4[rr] + ig * gg;
      c4[rr] = cc;
      float hn = og * tanh_fast(cc);
      float hnp = __shfl_xor(hn, 1);        // partner col's h
      hsave[rr] = hn;
      hpsave[rr] = hnp;
      if (wrp && q < 2 && t < 1023) {
        unsigned pack = (unsigned)f2bf(hn) | ((unsigned)f2bf(hnp) << 16);
        __hip_atomic_store(&hdst[(q * 4 + rr) * 256 + r * 16 + wave * 4 + ((lane & 6) >> 1)],
                           pack, __ATOMIC_RELAXED, __HIP_MEMORY_SCOPE_AGENT);
      }
    }

    if (t < 1023) {
      __syncthreads();                      // drains vmcnt(0): h stores ack'd at MALL
      if (tid == 0)
        __hip_atomic_store(&fl[r], (unsigned)(t + 1), __ATOMIC_RELAXED,
                           __HIP_MEMORY_SCOPE_AGENT);
    }

    // out stores after flag publish: retire during next step, off critical path
    if (wrp && q < 2) {
#pragma unroll
      for (int rr = 0; rr < 4; ++rr)
        *(float2*)&out[(long)(g * 8 + q * 4 + rr) * (NS * NH) + (long)t * NH +
                       r * 32 + wave * 8 + (lane & 6)] =
            make_float2(hsave[rr], hpsave[rr]);
    }

    if (t < 1023) {
      // prefetch next step's xg under the spin (read-only, cached)
      long xb2 = ((long)(t + 1) * 64) * 2048;
      if (q < 2) {
#pragma unroll
        for (int p = 0; p < 2; ++p)
#pragma unroll
          for (int rr = 0; rr < 4; ++rr)
            xpre[p][rr] = bf2f(xgg[xb2 + (long)(q * 4 + rr) * 2048 + gcol[p]]);
      }
      if (wave == 0 && lane < 16) {
        unsigned tgt = (unsigned)(t + 1);   // h_{t+1} slab ready from all 16 WGs
        while (__hip_atomic_load(&fl[lane], __ATOMIC_RELAXED,
                                 __HIP_MEMORY_SCOPE_AGENT) < tgt) {}
      }
      __syncthreads();
    }
  }

  // final h / c state (t = 1023 values still in registers)
  if (wr && q < 2) {
    int hcol = r * 32 + wave * 8 + (lane & 7);
#pragma unroll
    for (int rr = 0; rr < 4; ++rr) {
      int b = g * 8 + q * 4 + rr;
      out[OUT_HF + (long)b * 512 + hcol] = hsave[rr];
      out[OUT_CF + (long)b * 512 + hcol] = c4[rr];
    }
  }
}

extern "C" void kernel_launch(void* const* d_in, const int* in_sizes, int n_in,
                              void* d_out, int out_size, void* d_ws, size_t ws_size,
                              hipStream_t stream) {
  const float* inputs = (const float*)d_in[0];
  const float* Wxi = (const float*)d_in[1];
  const float* Whi = (const float*)d_in[2];
  const float* bi  = (const float*)d_in[3];
  const float* Wxf = (const float*)d_in[4];
  const float* Whf = (const float*)d_in[5];
  const float* bff = (const float*)d_in[6];
  const float* Wxo = (const float*)d_in[7];
  const float* Who = (const float*)d_in[8];
  const float* bo  = (const float*)d_in[9];
  const float* Wxc = (const float*)d_in[10];
  const float* Whc = (const float*)d_in[11];
  const float* bc  = (const float*)d_in[12];

  char* ws = (char*)d_ws;
  ushort*  Abf  = (ushort*)(ws + OFF_A);
  ushort*  xgp  = (ushort*)(ws + OFF_XG);
  ushort*  Wxt  = (ushort*)(ws + OFF_WXT);
  ushort*  Whtp = (ushort*)(ws + OFF_WHT);
  float*   bcat = (float*)(ws + OFF_BC);
  unsigned* hb  = (unsigned*)(ws + OFF_HB);
  unsigned* ctrl = (unsigned*)(ws + OFF_BAR);

  hipMemsetAsync(ctrl, 0, 1024, stream);   // flags[8][32]

  cvt_in_k<<<16384, 256, 0, stream>>>(inputs, Abf);
  prep_w_k<<<4096, 256, 0, stream>>>(Wxi, Whi, bi, Wxf, Whf, bff,
                                     Wxo, Who, bo, Wxc, Whc, bc,
                                     Wxt, Whtp, bcat);
  dim3 g1(M1 / 128, NG / 128);                                      // 512 x 16
  gemm_x_k<<<g1, 256, 0, stream>>>(Abf, Wxt, bcat, xgp);
  lstm_rec_k<<<128, 256, 0, stream>>>(xgp, Whtp, (float*)d_out, hb, ctrl);
}

// Round 10
// 3060.899 us; speedup vs baseline: 3.3562x; 1.1025x over previous
//
#include <hip/hip_runtime.h>
#include <hip/hip_bf16.h>

typedef __attribute__((ext_vector_type(8))) short short8;
typedef __attribute__((ext_vector_type(4))) float f32x4;
typedef __attribute__((ext_vector_type(4))) unsigned int u32x4;

// Problem dims
#define NB 64      // batch
#define NS 1024    // seq
#define ND 512     // input dim
#define NH 512     // hidden
#define NG 2048    // 4*NH gate columns
#define M1 65536   // NB*NS rows of the input-projection GEMM

// ws layout (bytes)
#define OFF_A    0L                      // A bf16 [65536][512] 64 MB; dead after gemm,
                                         // reused: hb3 u32 [8 grp][3][8][256] 192 KB
#define OFF_XG   67108864L               // xg bf16 [1024][64][2048]     256 MB
#define OFF_WXT  335544320L              // Wxt bf16 [2048][512]           2 MB
#define OFF_WHT  337641472L              // Wht bf16 [2048][512]           2 MB
#define OFF_BC   339738624L              // bcat f32 [2048]                8 KB

#define OUT_HF   33554432L               // d_out offset of h_final (floats)
#define OUT_CF   33587200L               // d_out offset of c_final

#define SENT32   0xFFFFFFFFu             // two bf16 NaNs: unreachable for h in (-1,1)
#define LDS_STRIDE 264                   // u32 row stride (1056B): read pattern max 2-way

static __device__ __forceinline__ ushort f2bf(float x) {
  union { float f; unsigned u; } v; v.f = x;
  unsigned r = (v.u + 0x7FFFu + ((v.u >> 16) & 1u)) >> 16;
  return (ushort)r;
}
static __device__ __forceinline__ float bf2f(ushort x) {
  union { unsigned u; float f; } v; v.u = ((unsigned)x) << 16; return v.f;
}
static __device__ __forceinline__ float sigm(float x) {
  return 1.0f / (1.0f + __expf(-x));
}
static __device__ __forceinline__ float tanh_fast(float x) {
  return 2.0f / (1.0f + __expf(-2.0f * x)) - 1.0f;
}

// ---------- phase 0a: fp32 -> bf16 convert of inputs ----------
__global__ __launch_bounds__(256) void cvt_in_k(const float* __restrict__ in,
                                                ushort* __restrict__ out) {
  long i = ((long)blockIdx.x * 256 + threadIdx.x) * 8;
  const float4* p = (const float4*)(in + i);
  float4 a = p[0], b = p[1];
  short8 o;
  o[0] = (short)f2bf(a.x); o[1] = (short)f2bf(a.y);
  o[2] = (short)f2bf(a.z); o[3] = (short)f2bf(a.w);
  o[4] = (short)f2bf(b.x); o[5] = (short)f2bf(b.y);
  o[6] = (short)f2bf(b.z); o[7] = (short)f2bf(b.w);
  *(short8*)(out + i) = o;
}

// ---------- phase 0b: transpose+convert weights, pack biases ----------
__global__ __launch_bounds__(256) void prep_w_k(
    const float* __restrict__ Wxi, const float* __restrict__ Whi, const float* __restrict__ bi,
    const float* __restrict__ Wxf, const float* __restrict__ Whf, const float* __restrict__ bff,
    const float* __restrict__ Wxo, const float* __restrict__ Who, const float* __restrict__ bo,
    const float* __restrict__ Wxc, const float* __restrict__ Whc, const float* __restrict__ bc,
    ushort* __restrict__ Wxt, ushort* __restrict__ Wht, float* __restrict__ bcat) {
  int t = blockIdx.x * 256 + threadIdx.x;   // 0 .. 2048*512-1
  int n = t >> 9, k = t & 511;
  int g = n >> 9, col = n & 511;
  const float* wx = (g == 0) ? Wxi : (g == 1) ? Wxf : (g == 2) ? Wxo : Wxc;
  const float* wh = (g == 0) ? Whi : (g == 1) ? Whf : (g == 2) ? Who : Whc;
  Wxt[t] = f2bf(wx[k * 512 + col]);
  Wht[t] = f2bf(wh[k * 512 + col]);
  if (t < 2048) {
    int g2 = t >> 9;
    const float* bp = (g2 == 0) ? bi : (g2 == 1) ? bff : (g2 == 2) ? bo : bc;
    bcat[t] = bp[t & 511];
  }
}

// ---------- phase 1: xg = A @ Wxt^T + b  (bf16 MFMA, 128x128 tiles, BK=32) ----------
__global__ __launch_bounds__(256) void gemm_x_k(const ushort* __restrict__ A,
                                                const ushort* __restrict__ Bt,
                                                const float* __restrict__ bcat,
                                                ushort* __restrict__ xg) {
  __shared__ ushort As[128 * 40];
  __shared__ ushort Bs[128 * 40];
  const int mbase = blockIdx.x * 128;
  const int nbase = blockIdx.y * 128;
  const int tid = threadIdx.x;
  const int lane = tid & 63, wave = tid >> 6;
  const int l15 = lane & 15, q = lane >> 4;
  const int wm = (wave & 1) * 64, wn = (wave >> 1) * 64;

  f32x4 acc[4][4];
#pragma unroll
  for (int j = 0; j < 4; ++j) {
    float bv = bcat[nbase + wn + j * 16 + l15];
#pragma unroll
    for (int i = 0; i < 4; ++i) acc[i][j] = (f32x4){bv, bv, bv, bv};
  }

  const int sr = tid >> 2;
  const int skk = (tid & 3) * 8;

  for (int kt = 0; kt < 16; ++kt) {
    const int kb = kt * 32;
#pragma unroll
    for (int pass = 0; pass < 2; ++pass) {
      int rr = sr + pass * 64;
      *(short8*)&As[rr * 40 + skk] = *(const short8*)&A[(long)(mbase + rr) * 512 + kb + skk];
      *(short8*)&Bs[rr * 40 + skk] = *(const short8*)&Bt[(long)(nbase + rr) * 512 + kb + skk];
    }
    __syncthreads();
    short8 af[4], bfr[4];
#pragma unroll
    for (int i = 0; i < 4; ++i)
      af[i] = *(const short8*)&As[(wm + i * 16 + l15) * 40 + q * 8];
#pragma unroll
    for (int j = 0; j < 4; ++j)
      bfr[j] = *(const short8*)&Bs[(wn + j * 16 + l15) * 40 + q * 8];
#pragma unroll
    for (int i = 0; i < 4; ++i)
#pragma unroll
      for (int j = 0; j < 4; ++j)
        acc[i][j] = __builtin_amdgcn_mfma_f32_16x16x32_bf16(af[i], bfr[j], acc[i][j], 0, 0, 0);
    __syncthreads();
  }

#pragma unroll
  for (int i = 0; i < 4; ++i) {
#pragma unroll
    for (int r = 0; r < 4; ++r) {
      int m = mbase + wm + i * 16 + q * 4 + r;
      int b = m >> 10, s = m & 1023;
      long rowoff = ((long)(s * 64 + b)) * 2048;
#pragma unroll
      for (int j = 0; j < 4; ++j) {
        int n = nbase + wn + j * 16 + l15;
        xg[rowoff + n] = f2bf(acc[i][j][r]);
      }
    }
  }
}

// ---------- phase 2: persistent recurrence, sentinel-merged cooperative staging ----------
// 128 WGs = 8 groups x 16 roles (R9 geometry + LDS slab dedup). NEW vs R9: the
// flag protocol is GONE. Depth-3 rotating slabs hb3[g][t%3][8][256] are
// pre-poisoned with SENT32 (two bf16 NaNs, unreachable). Producers fire-and-
// forget h-stores (sc0 sc1); readers run the SAME cooperative 2x dwordx4
// staging but retry until sentinel-free -> detection and data are ONE load
// (saves the drain-before-flag RT and the flag RT). Re-poison: each WG, after
// staging slab t, re-poisons its own 512B share of parity (t-1)%3; safe since
// slab t clean => all consumed t-1. A vmcnt(0) before the h-stores (cheap:
// poison issued a full compute-phase earlier) orders poison < publish, so a
// consumer that sees slab t+1 clean implies every poison of parity (t+1)%3's
// previous tenant completed. Every slab word has exactly one producer (16 WGs
// x 128 u32 = 2048 = full slab) => retries terminate => no deadlock.
// Barriers are lgkmcnt-only (LDS ordering) - no vmem drain on the chain.
__global__ __launch_bounds__(256, 1) void lstm_rec_k(const ushort* __restrict__ xg,
                                                     const ushort* __restrict__ Wht,
                                                     float* __restrict__ out,
                                                     unsigned* hb3) {
  const int wg = blockIdx.x;          // 0..127
  const int g = wg & 7, r = wg >> 3;  // group, role
  const int tid = threadIdx.x;
  const int wave = tid >> 6, lane = tid & 63;
  const int l15 = lane & 15, q = lane >> 4;

  __shared__ unsigned hs[8 * LDS_STRIDE];   // staged h slab, 8 rows x 256 u32 (+pad)

  unsigned* hbg = hb3 + g * 6144;     // [3 parity][8 rows][256 u32] = 24KB/group
  const ushort* xgg = xg + (long)g * 8 * 2048;  // group's batch-0 column

  // --- B fragments: this wave's 32 gate-cols (gates packed pairwise), pinned ---
  short8 bfrag[2][16];
  int gcol[2];
#pragma unroll
  for (int p = 0; p < 2; ++p) {
    int nloc = p * 16 + l15;
    gcol[p] = (nloc >> 3) * 512 + r * 32 + wave * 8 + (nloc & 7);
#pragma unroll
    for (int kt = 0; kt < 16; ++kt)
      bfrag[p][kt] = *(const short8*)&Wht[(long)gcol[p] * 512 + kt * 32 + q * 8];
  }
#pragma unroll
  for (int p = 0; p < 2; ++p)
#pragma unroll
    for (int kt = 0; kt < 16; ++kt)
      asm volatile("" : "+v"(bfrag[p][kt]));

  // prefetch xg[t=0] (h_0 == 0 implicit: no loads, no init handshake)
  float xpre[2][4] = {{0.f, 0.f, 0.f, 0.f}, {0.f, 0.f, 0.f, 0.f}};
  if (q < 2) {
#pragma unroll
    for (int p = 0; p < 2; ++p)
#pragma unroll
      for (int rr = 0; rr < 4; ++rr)
        xpre[p][rr] = bf2f(xgg[(long)(q * 4 + rr) * 2048 + gcol[p]]);
  }

  const bool wr = (lane & 8) == 0;          // gate-dedup writer lanes
  const bool wrp = wr && ((lane & 1) == 0); // pair writer lanes (u32 / float2)
  float c4[4] = {0.f, 0.f, 0.f, 0.f};
  float hsave[4] = {0.f, 0.f, 0.f, 0.f};
  float hpsave[4] = {0.f, 0.f, 0.f, 0.f};

  // staging chunk ids: thread handles 16B chunks tid and tid+256 (512 total)
  const int c0 = tid, c1 = tid + 256;
  const int l0 = (c0 >> 6) * LDS_STRIDE + (c0 & 63) * 4;  // LDS u32 index
  const int l1 = (c1 >> 6) * LDS_STRIDE + (c1 & 63) * 4;
  const int woff = q * 1024 + r * 16 + wave * 4 + ((lane & 6) >> 1);  // writer u32 off

  for (int t = 0; t < 1024; ++t) {
    union { unsigned long long u[2]; short8 s8; } afu[16];

    if (t > 0) {
      // ---- cooperative staging with sentinel retry: detect + load fused ----
      const unsigned* gb = hbg + (t % 3) * 2048;
      u32x4 va, vb;
      unsigned bad;
      do {
        asm volatile(
            "global_load_dwordx4 %0, %2, off sc0 sc1\n\t"
            "global_load_dwordx4 %1, %3, off sc0 sc1\n\t"
            "s_waitcnt vmcnt(0)"
            : "=&v"(va), "=&v"(vb)
            : "v"(gb + c0 * 4), "v"(gb + c1 * 4)
            : "memory");
        bad = 0;
#pragma unroll
        for (int i = 0; i < 4; ++i) {
          bad |= (unsigned)(va[i] == SENT32);
          bad |= (unsigned)(vb[i] == SENT32);
        }
      } while (bad);
      *(u32x4*)&hs[l0] = va;
      *(u32x4*)&hs[l1] = vb;
      asm volatile("s_waitcnt lgkmcnt(0)\n\ts_barrier" ::: "memory");  // slab staged

      if (l15 < 8) {
        const unsigned* lb = &hs[l15 * LDS_STRIDE + q * 4];
#pragma unroll
        for (int kt = 0; kt < 16; ++kt)
          afu[kt].s8 = *(const short8*)(lb + kt * 16);
      } else {
#pragma unroll
        for (int kt = 0; kt < 16; ++kt) { afu[kt].u[0] = 0ull; afu[kt].u[1] = 0ull; }
      }

      // ---- re-poison own share of the slab consumed last step (parity (t-1)%3) ----
      // Safe: slab t clean => all 16 WGs consumed t-1. Ordered before our next
      // h-publish by the vmcnt(0) below.
      if (wrp && q < 2) {
        unsigned* pp = hbg + ((t + 2) % 3) * 2048 + woff;
        asm volatile(
            "global_store_dword %[a], %[s], off sc0 sc1\n\t"
            "global_store_dword %[a], %[s], off offset:1024 sc0 sc1\n\t"
            "global_store_dword %[a], %[s], off offset:2048 sc0 sc1\n\t"
            "global_store_dword %[a], %[s], off offset:3072 sc0 sc1"
            :: [a]"v"(pp), [s]"v"(SENT32) : "memory");
      }
    } else {
#pragma unroll
      for (int kt = 0; kt < 16; ++kt) { afu[kt].u[0] = 0ull; afu[kt].u[1] = 0ull; }
    }

    f32x4 acc[2];
#pragma unroll
    for (int p = 0; p < 2; ++p)
#pragma unroll
      for (int rr = 0; rr < 4; ++rr)
        acc[p][rr] = xpre[p][rr];

#pragma unroll
    for (int kt = 0; kt < 16; ++kt) {
      acc[0] = __builtin_amdgcn_mfma_f32_16x16x32_bf16(afu[kt].s8, bfrag[0][kt], acc[0], 0, 0, 0);
      acc[1] = __builtin_amdgcn_mfma_f32_16x16x32_bf16(afu[kt].s8, bfrag[1][kt], acc[1], 0, 0, 0);
    }

    // elementwise: lane (bit3=0) has i (acc0), o (acc1); partner lane^8 has f, g.
    unsigned packs[4];
#pragma unroll
    for (int rr = 0; rr < 4; ++rr) {
      float a0 = acc[0][rr], a1 = acc[1][rr];
      float o0 = __shfl_xor(a0, 8);
      float o1 = __shfl_xor(a1, 8);
      float pi = wr ? a0 : o0;
      float pf = wr ? o0 : a0;
      float po = wr ? a1 : o1;
      float pg = wr ? o1 : a1;
      float ig = sigm(pi), fg = sigm(pf), og = sigm(po), gg = tanh_fast(pg);
      float cc = fg * c4[rr] + ig * gg;
      c4[rr] = cc;
      float hn = og * tanh_fast(cc);
      float hnp = __shfl_xor(hn, 1);        // partner col's h
      hsave[rr] = hn;
      hpsave[rr] = hnp;
      packs[rr] = (unsigned)f2bf(hn) | ((unsigned)f2bf(hnp) << 16);
    }

    // ---- publish h_{t+1}: fire-and-forget. vmcnt(0) first (cheap: everything
    // outstanding is >= one compute-phase old) orders poison < publish. ----
    if (t < 1023 && wrp && q < 2) {
      unsigned* hd = hbg + ((t + 1) % 3) * 2048 + woff;
      asm volatile(
          "s_waitcnt vmcnt(0)\n\t"
          "global_store_dword %[a], %[d0], off sc0 sc1\n\t"
          "global_store_dword %[a], %[d1], off offset:1024 sc0 sc1\n\t"
          "global_store_dword %[a], %[d2], off offset:2048 sc0 sc1\n\t"
          "global_store_dword %[a], %[d3], off offset:3072 sc0 sc1"
          :: [a]"v"(hd), [d0]"v"(packs[0]), [d1]"v"(packs[1]),
             [d2]"v"(packs[2]), [d3]"v"(packs[3])
          : "memory");
    }

    // out stores + xg prefetch: fire-and-forget, retire under next retry window
    if (wrp && q < 2) {
#pragma unroll
      for (int rr = 0; rr < 4; ++rr)
        *(float2*)&out[(long)(g * 8 + q * 4 + rr) * (NS * NH) + (long)t * NH +
                       r * 32 + wave * 8 + (lane & 6)] =
            make_float2(hsave[rr], hpsave[rr]);
    }

    if (t < 1023) {
      long xb2 = ((long)(t + 1) * 64) * 2048;
      if (q < 2) {
#pragma unroll
        for (int p = 0; p < 2; ++p)
#pragma unroll
          for (int rr = 0; rr < 4; ++rr)
            xpre[p][rr] = bf2f(xgg[xb2 + (long)(q * 4 + rr) * 2048 + gcol[p]]);
      }
      // LDS reuse guard only (no vmem drain): all waves' ds_reads done
      asm volatile("s_waitcnt lgkmcnt(0)\n\ts_barrier" ::: "memory");
    }
  }

  // final h / c state (t = 1023 values still in registers)
  if (wr && q < 2) {
    int hcol = r * 32 + wave * 8 + (lane & 7);
#pragma unroll
    for (int rr = 0; rr < 4; ++rr) {
      int b = g * 8 + q * 4 + rr;
      out[OUT_HF + (long)b * 512 + hcol] = hsave[rr];
      out[OUT_CF + (long)b * 512 + hcol] = c4[rr];
    }
  }
}

extern "C" void kernel_launch(void* const* d_in, const int* in_sizes, int n_in,
                              void* d_out, int out_size, void* d_ws, size_t ws_size,
                              hipStream_t stream) {
  const float* inputs = (const float*)d_in[0];
  const float* Wxi = (const float*)d_in[1];
  const float* Whi = (const float*)d_in[2];
  const float* bi  = (const float*)d_in[3];
  const float* Wxf = (const float*)d_in[4];
  const float* Whf = (const float*)d_in[5];
  const float* bff = (const float*)d_in[6];
  const float* Wxo = (const float*)d_in[7];
  const float* Who = (const float*)d_in[8];
  const float* bo  = (const float*)d_in[9];
  const float* Wxc = (const float*)d_in[10];
  const float* Whc = (const float*)d_in[11];
  const float* bc  = (const float*)d_in[12];

  char* ws = (char*)d_ws;
  ushort*  Abf  = (ushort*)(ws + OFF_A);
  ushort*  xgp  = (ushort*)(ws + OFF_XG);
  ushort*  Wxt  = (ushort*)(ws + OFF_WXT);
  ushort*  Whtp = (ushort*)(ws + OFF_WHT);
  float*   bcat = (float*)(ws + OFF_BC);
  unsigned* hb3 = (unsigned*)(ws + OFF_A);   // 192KB in dead A region

  cvt_in_k<<<16384, 256, 0, stream>>>(inputs, Abf);
  prep_w_k<<<4096, 256, 0, stream>>>(Wxi, Whi, bi, Wxf, Whf, bff,
                                     Wxo, Who, bo, Wxc, Whc, bc,
                                     Wxt, Whtp, bcat);
  dim3 g1(M1 / 128, NG / 128);                                      // 512 x 16
  gemm_x_k<<<g1, 256, 0, stream>>>(Abf, Wxt, bcat, xgp);
  // A region dead: poison all 3 slab parities (8 grp x 3 x 8KB). Stream-ordered.
  hipMemsetAsync(hb3, 0xFF, 196608, stream);
  lstm_rec_k<<<128, 256, 0, stream>>>(xgp, Whtp, (float*)d_out, hb3);
}